// Round 6
// baseline (191.385 us; speedup 1.0000x reference)
//
#include <hip/hip_runtime.h>
#include <hip/hip_bf16.h>

typedef __attribute__((ext_vector_type(8))) short bf16x8;
typedef __attribute__((ext_vector_type(4))) float f32x4;
typedef float f32x4u __attribute__((ext_vector_type(4), aligned(4))); // x rows are only 4B-aligned (LL odd)
typedef __attribute__((ext_vector_type(4))) short short4v;
typedef unsigned short ushort_t;

#define CC 120
#define LL 469
#define HH 64

constexpr int NBATCH = 1024;           // (s,b) pairs; raw reshape => batch contiguous
constexpr int KSTEPS = (LL + 31) / 32; // 15

// ---- LDS layout ----
// phase 1: per-wave X tiles: Xw[wave][2 buf][32 rows][40 shorts] bf16 = 4*2*2560 B = 20480 B.
//          No W in LDS (fragments loaded global->VGPR from L2-resident image).
//          NO BARRIERS in the K loop: all phase-1 LDS deps are same-wave.
// phase 2: Qb @0 (16 KB, [128]x128B swz), Kb @16384, Vb @32768 ([64]x256B swz)
//          Pb @0 (32 KB) aliases Q+K after QK^T barrier
// epilogue: Ob f32 [120][68] @0
constexpr int SMEM_BYTES = 49152;
// W image: [t][n][lane][8] bf16 fragments, 15*12*64*8 shorts = 92160 (184320 B)
constexpr int WIMG_SHORTS = KSTEPS * 12 * 64 * 8;
constexpr int WIMG_BYTES  = WIMG_SHORTS * 2;

__device__ __forceinline__ ushort_t f2bf(float f) {
  __hip_bfloat16 h = __float2bfloat16(f);
  return __builtin_bit_cast(ushort_t, h);
}

// XOR-swizzled LDS address for phase-2 tiles
__device__ __forceinline__ char* sptr(char* base, int row, int stride, int byteoff) {
  return base + row * stride + (byteoff ^ ((row & 7) << 4));
}

// Build W fragment image: wimg[((t*12+n)*64 + lane)*8 + j] = Wcat[t*32 + (lane>>4)*8 + j][n*16 + (lane&15)]
__global__ void prep_w(const float* __restrict__ Wk, const float* __restrict__ Wq,
                       const float* __restrict__ Wv, ushort_t* __restrict__ wimg) {
  int idx = blockIdx.x * 256 + threadIdx.x; // 92160 exactly (360 blocks)
  int j = idx & 7;
  int lane = (idx >> 3) & 63;
  int tn = idx >> 9;
  int n = tn % 12;
  int t = tn / 12;
  int lr = lane & 15, lg = lane >> 4;
  int k = t * 32 + lg * 8 + j;
  int col = n * 16 + lr;
  int wsel = col >> 6, h = col & 63;
  const float* wp = (wsel == 0) ? Wk : (wsel == 1) ? Wq : Wv;
  float v = (k < LL) ? wp[(size_t)k * HH + h] : 0.f;
  wimg[idx] = f2bf(v);
}

template <bool WIMG>
__global__ __launch_bounds__(256, 3)
void fused_regional_head(const float* __restrict__ x,
                         const float* __restrict__ Wk,
                         const float* __restrict__ Wq,
                         const float* __restrict__ Wv,
                         const ushort_t* __restrict__ wimg,
                         float* __restrict__ out) {
  __shared__ char smem[SMEM_BYTES];
  const int tid = threadIdx.x;
  const int lane = tid & 63;
  const int wv = tid >> 6;   // wave 0..3, owns rows 32*wv .. 32*wv+31
  const int lr = lane & 15;
  const int lg = lane >> 4;
  const int batch = blockIdx.x;
  const size_t xbase = (size_t)batch * CC * LL;

  // per-wave X staging region: [2 buf][32 rows][40 shorts]
  ushort_t* Xw = (ushort_t*)smem + wv * 2 * 1280;

  // staging map: lane covers chunk (lane&7) of rows s*8 + (lane>>3), s=0..3
  const int schunk = lane & 7;       // 16B chunk within row (k = chunk*4..chunk*4+3)
  const int srow = lane >> 3;        // 0..7

  // coalesced global load of this wave's next X tile (4 x 16B per lane)
  auto xload = [&](int t, f32x4u* v) {
    const f32x4u z = (f32x4u){0.f, 0.f, 0.f, 0.f};
    if (t == KSTEPS - 1) { // tail: k = 448..468, guarded scalar loads
#pragma unroll
      for (int s = 0; s < 4; ++s) {
        int row = wv * 32 + s * 8 + srow;
        v[s] = z;
        if (row < CC) {
#pragma unroll
          for (int j = 0; j < 4; ++j) {
            int k = 448 + schunk * 4 + j;
            if (k < LL) v[s][j] = x[xbase + (size_t)row * LL + k];
          }
        }
      }
    } else {
      const int k0 = t * 32 + schunk * 4;
#pragma unroll
      for (int s = 0; s < 4; ++s) {
        int row = wv * 32 + s * 8 + srow;
        v[s] = (row < CC) ? *(const f32x4u*)(x + xbase + (size_t)row * LL + k0) : z;
      }
    }
  };
  // cvt + per-wave LDS write (ds_write_b64), same-wave dep only
  auto xwrite = [&](int buf, const f32x4u* v) {
    ushort_t* xb = Xw + buf * 1280;
#pragma unroll
    for (int s = 0; s < 4; ++s) {
      short4v pk;
#pragma unroll
      for (int j = 0; j < 4; ++j) pk[j] = (short)f2bf(v[s][j]);
      *(short4v*)(xb + (s * 8 + srow) * 40 + schunk * 4) = pk;
    }
  };

  // ---------------- phase 1: QKV = X @ [Wk|Wq|Wv], BARRIER-FREE ----------------
  f32x4 acc[2][12];
#pragma unroll
  for (int m = 0; m < 2; ++m)
#pragma unroll
    for (int n = 0; n < 12; ++n) acc[m][n] = (f32x4){0.f, 0.f, 0.f, 0.f};

  f32x4u xv[4];
  xload(0, xv);
  xwrite(0, xv);

  const char* wfb = (const char*)wimg + (size_t)lane * 16; // fragment base for this lane

#pragma unroll
  for (int t = 0; t < KSTEPS; ++t) {
    const ushort_t* xb = Xw + (t & 1) * 1280;
    bf16x8 a0 = *(const bf16x8*)(xb + lr * 40 + lg * 8);
    bf16x8 a1 = *(const bf16x8*)(xb + (16 + lr) * 40 + lg * 8);
    if (t + 1 < KSTEPS) xload(t + 1, xv); // overlap with W loads + MFMA
    bf16x8 w[12];
    if constexpr (WIMG) {
      const char* wt = wfb + (size_t)t * 12288; // 12 frags x 1024B
#pragma unroll
      for (int n = 0; n < 12; ++n) w[n] = *(const bf16x8*)(wt + n * 1024);
    } else {
#pragma unroll
      for (int n = 0; n < 12; ++n) {
        int col = n * 16 + lr;
        int wsel = col >> 6, h = col & 63;
        const float* wp = (wsel == 0) ? Wk : (wsel == 1) ? Wq : Wv;
#pragma unroll
        for (int j = 0; j < 8; ++j) {
          int k = t * 32 + lg * 8 + j;
          w[n][j] = (short)f2bf((k < LL) ? wp[(size_t)k * HH + h] : 0.f);
        }
      }
    }
#pragma unroll
    for (int n = 0; n < 12; ++n) {
      acc[0][n] = __builtin_amdgcn_mfma_f32_16x16x32_bf16(a0, w[n], acc[0][n], 0, 0, 0);
      acc[1][n] = __builtin_amdgcn_mfma_f32_16x16x32_bf16(a1, w[n], acc[1][n], 0, 0, 0);
    }
    if (t + 1 < KSTEPS) xwrite((t + 1) & 1, xv);
  }
  __syncthreads(); // phase-1 per-wave regions dead; phase-2 tiles take over

  // ---------------- write Q,K,V (bf16, swizzled) ----------------
  char* Qb = smem;
  char* Kb = smem + 16384;
  char* Vb = smem + 32768;
  char* Pb = smem;
#pragma unroll
  for (int mt = 0; mt < 2; ++mt) {
#pragma unroll
    for (int r = 0; r < 4; ++r) {
      int row = wv * 32 + mt * 16 + lg * 4 + r;
#pragma unroll
      for (int n = 0; n < 4; ++n) {
        *(ushort_t*)sptr(Kb, row, 128, (n * 16 + lr) * 2) = f2bf(acc[mt][n][r]);
        *(ushort_t*)sptr(Qb, row, 128, (n * 16 + lr) * 2) = f2bf(acc[mt][4 + n][r]);
      }
    }
    // V^T packed: 4 consecutive d-rows -> ds_write_b64
#pragma unroll
    for (int n = 0; n < 4; ++n) {
      short4v pk;
#pragma unroll
      for (int r = 0; r < 4; ++r) pk[r] = (short)f2bf(acc[mt][8 + n][r]);
      *(short4v*)sptr(Vb, n * 16 + lr, 256, (wv * 32 + mt * 16 + lg * 4) * 2) = pk;
    }
  }
  __syncthreads();

  // ---------------- QK^T ----------------
  f32x4 accw[2][8];
#pragma unroll
  for (int m = 0; m < 2; ++m)
#pragma unroll
    for (int n = 0; n < 8; ++n) accw[m][n] = (f32x4){0.f, 0.f, 0.f, 0.f};
#pragma unroll
  for (int ks = 0; ks < 2; ++ks) {
    bf16x8 a0 = *(const bf16x8*)sptr(Qb, wv * 32 + lr, 128, ks * 64 + lg * 16);
    bf16x8 a1 = *(const bf16x8*)sptr(Qb, wv * 32 + 16 + lr, 128, ks * 64 + lg * 16);
#pragma unroll
    for (int n = 0; n < 8; ++n) {
      bf16x8 b = *(const bf16x8*)sptr(Kb, n * 16 + lr, 128, ks * 64 + lg * 16);
      accw[0][n] = __builtin_amdgcn_mfma_f32_16x16x32_bf16(a0, b, accw[0][n], 0, 0, 0);
      accw[1][n] = __builtin_amdgcn_mfma_f32_16x16x32_bf16(a1, b, accw[1][n], 0, 0, 0);
    }
  }
  __syncthreads(); // all done reading Q/K before P overwrites

  // ---------------- softmax (wave-parallel over 16-lane col groups) ----------------
#pragma unroll
  for (int mt = 0; mt < 2; ++mt)
#pragma unroll
    for (int r = 0; r < 4; ++r) {
      float l[8];
      float m = -1e30f;
#pragma unroll
      for (int n = 0; n < 8; ++n) {
        float v = accw[mt][n][r] * 0.125f;
        if (n == 7 && lr >= 8) v = -1e30f; // col = 112+lr >= 120 masked
        l[n] = v;
        m = fmaxf(m, v);
      }
#pragma unroll
      for (int off = 1; off < 16; off <<= 1) m = fmaxf(m, __shfl_xor(m, off));
      float s = 0.f;
#pragma unroll
      for (int n = 0; n < 8; ++n) {
        float p = __expf(l[n] - m);
        l[n] = p;
        s += p;
      }
#pragma unroll
      for (int off = 1; off < 16; off <<= 1) s += __shfl_xor(s, off);
      float inv = 1.f / s;
      int row = wv * 32 + mt * 16 + lg * 4 + r;
#pragma unroll
      for (int n = 0; n < 8; ++n)
        *(ushort_t*)sptr(Pb, row, 256, (n * 16 + lr) * 2) = f2bf(l[n] * inv);
    }
  // no barrier: each wave reads only its own P rows; V covered by barrier above

  // ---------------- out = P @ V ----------------
  f32x4 acco[2][4];
#pragma unroll
  for (int m = 0; m < 2; ++m)
#pragma unroll
    for (int n = 0; n < 4; ++n) acco[m][n] = (f32x4){0.f, 0.f, 0.f, 0.f};
#pragma unroll
  for (int ks = 0; ks < 4; ++ks) {
    bf16x8 a0 = *(const bf16x8*)sptr(Pb, wv * 32 + lr, 256, ks * 64 + lg * 16);
    bf16x8 a1 = *(const bf16x8*)sptr(Pb, wv * 32 + 16 + lr, 256, ks * 64 + lg * 16);
#pragma unroll
    for (int n = 0; n < 4; ++n) {
      bf16x8 b = *(const bf16x8*)sptr(Vb, n * 16 + lr, 256, ks * 64 + lg * 16);
      acco[0][n] = __builtin_amdgcn_mfma_f32_16x16x32_bf16(a0, b, acco[0][n], 0, 0, 0);
      acco[1][n] = __builtin_amdgcn_mfma_f32_16x16x32_bf16(a1, b, acco[1][n], 0, 0, 0);
    }
  }

  // ---------------- epilogue: LDS transpose -> float4 coalesced stores ----------------
  __syncthreads(); // P/V dead
  float* Ob = (float*)smem; // [120][68] f32
#pragma unroll
  for (int mt = 0; mt < 2; ++mt)
#pragma unroll
    for (int r = 0; r < 4; ++r) {
      int row = wv * 32 + mt * 16 + lg * 4 + r;
      if (row < CC) {
#pragma unroll
        for (int n = 0; n < 4; ++n)
          Ob[row * 68 + n * 16 + lr] = acco[mt][n][r];
      }
    }
  __syncthreads();
  const size_t obase = (size_t)batch * CC * HH;
#pragma unroll
  for (int i = 0; i < 8; ++i) {
    int idx = i * 256 + tid; // float4 index, 1920 total
    if (idx < 1920) {
      int row = idx >> 4;
      int c4 = (idx & 15) * 4;
      f32x4 v = *(const f32x4*)(Ob + row * 68 + c4);
      *(f32x4*)(out + obase + (size_t)idx * 4) = v;
    }
  }
}

extern "C" void kernel_launch(void* const* d_in, const int* in_sizes, int n_in,
                              void* d_out, int out_size, void* d_ws, size_t ws_size,
                              hipStream_t stream) {
  (void)in_sizes; (void)n_in; (void)out_size;
  const float* x  = (const float*)d_in[0];
  const float* Wk = (const float*)d_in[1];
  const float* Wq = (const float*)d_in[2];
  const float* Wv = (const float*)d_in[3];
  float* out = (float*)d_out;
  if (ws_size >= (size_t)WIMG_BYTES && d_ws != nullptr) {
    ushort_t* wimg = (ushort_t*)d_ws;
    prep_w<<<360, 256, 0, stream>>>(Wk, Wq, Wv, wimg);
    fused_regional_head<true><<<NBATCH, 256, 0, stream>>>(x, Wk, Wq, Wv, wimg, out);
  } else {
    fused_regional_head<false><<<NBATCH, 256, 0, stream>>>(x, Wk, Wq, Wv, nullptr, out);
  }
}